// Round 9
// baseline (230.727 us; speedup 1.0000x reference)
//
#include <hip/hip_runtime.h>
#include <hip/hip_bf16.h>

typedef __bf16 bf16;
typedef __attribute__((ext_vector_type(8))) __bf16 bf16x8;
typedef __attribute__((ext_vector_type(4))) __bf16 bf16x4;
typedef __attribute__((ext_vector_type(2))) __bf16 bf16x2;
typedef __attribute__((ext_vector_type(4))) float f32x4;
typedef __attribute__((ext_vector_type(2))) unsigned int u32x2;
typedef __attribute__((ext_vector_type(4))) unsigned int u32x4;

#define MFMA16(a, b, c) __builtin_amdgcn_mfma_f32_16x16x32_bf16((a), (b), (c), 0, 0, 0)
#define SM_SCALE 0.18033688011112043f  // (1/8) * log2(e), folded into q at GEMM epilogue

__device__ __forceinline__ void gld_lds16(const bf16* g, bf16* l) {
    __builtin_amdgcn_global_load_lds((const __attribute__((address_space(1))) void*)g,
                                     (__attribute__((address_space(3))) void*)l, 16, 0, 0);
}

// raw barriers: no compiler-inserted vmcnt(0)/lgkmcnt(0) drain at each barrier.
#define PBAR() asm volatile("s_barrier" ::: "memory")
#define VWAIT0() asm volatile("s_waitcnt vmcnt(0)" ::: "memory")
#define VWAIT2() asm volatile("s_waitcnt vmcnt(2)" ::: "memory")
#define VWAIT3() asm volatile("s_waitcnt vmcnt(3)" ::: "memory")
#define VWAIT4() asm volatile("s_waitcnt vmcnt(4)" ::: "memory")

// ---------------- prep: W transpose (blocks 0..767) + x f32->bf16 (blocks 768..2815) --------
__global__ __launch_bounds__(256) void prep(const float* __restrict__ W0,
                                            const float* __restrict__ W1,
                                            const float* __restrict__ W2,
                                            bf16* __restrict__ Wt,
                                            const float* __restrict__ xin,
                                            bf16* __restrict__ xout) {
    __shared__ float tile[64][65];
    const int blk = blockIdx.x;
    const int tid = threadIdx.x;
    if (blk < 768) {
        const int z = blk >> 8, rem = blk & 255;
        const int r0 = (rem >> 4) * 64;  // k
        const int c0 = (rem & 15) * 64;  // n
        const float* W = (z == 0) ? W0 : ((z == 1) ? W1 : W2);
        bf16* dst = Wt + (size_t)z * 1024 * 1024;
        for (int i = tid; i < 4096; i += 256) {
            int r = i >> 6, cc = i & 63;
            tile[r][cc] = W[(size_t)(r0 + r) * 1024 + c0 + cc];
        }
        __syncthreads();
        for (int i = tid; i < 4096; i += 256) {
            int n = i >> 6, k = i & 63;
            dst[(size_t)(c0 + n) * 1024 + r0 + k] = (bf16)tile[k][n];
        }
    } else {
        // 2048 blocks x 256 threads x 16 floats = 8,388,608 = 8192*1024 exactly
        const size_t i0 = ((size_t)(blk - 768) * 256 + tid) * 16;
#pragma unroll
        for (int j = 0; j < 2; j++) {
            const float4 v0 = *(const float4*)(xin + i0 + j * 8);
            const float4 v1 = *(const float4*)(xin + i0 + j * 8 + 4);
            bf16x8 o = {(bf16)v0.x, (bf16)v0.y, (bf16)v0.z, (bf16)v0.w,
                        (bf16)v1.x, (bf16)v1.y, (bf16)v1.z, (bf16)v1.w};
            *(bf16x8*)(xout + i0 + j * 8) = o;
        }
    }
}

// ---------------- QKV GEMM: 256x192 tile, BK=32, 12 waves (4Mx3N), 64x64/wave ----------------
// R16: MFMA-dominant regeometry. Per CU per K-step: LDS reads 12 waves x 8KB = 768cy
// < MFMA 12x16 x 4.85 = 931cy (was 1024 vs 931 -> LDS-pipe bound). Grid 512 = 2 EXACT
// rounds at 1 block/CU (LDS 86KB), no tail (was 768 blocks = 1.5 rounds). 3 waves/SIMD.
// Staging wave-role split: waves 0-3 stage B (3 gld_lds each: 12KB), waves 4-11 stage A
// (2 each: 16KB); counted drain is wave-uniform branch vmcnt(3)/vmcnt(2). Same 3-buf
// depth-2 pipeline + conflict-free ((row>>1)&3) XOR swizzle. Epilogue: q/k/v selected
// per 16-col fragment (1024-boundaries fragment-aligned; sel wave-uniform).
__global__ __launch_bounds__(768, 3) void gemm_qkv(const bf16* __restrict__ A,
                                                   const bf16* __restrict__ Bt,
                                                   const float* __restrict__ b0,
                                                   const float* __restrict__ b1,
                                                   const float* __restrict__ b2,
                                                   bf16* __restrict__ qb,
                                                   bf16* __restrict__ kb,
                                                   bf16* __restrict__ Vt) {
    __shared__ alignas(16) bf16 LDS[3 * 14336];  // per buf: A 256x32 @0 | B 192x32 @8192

    // XCD-chunked bijective swizzle: 512 blocks, 64/XCD (4 M-rows x 16 N-cols).
    const int orig = blockIdx.x;
    const int swz = (orig & 7) * 64 + (orig >> 3);
    const int by = swz >> 4, bx = swz & 15;
    const int m0 = by * 256, n0 = bx * 192;

    const int tid = threadIdx.x;
    const int wid = tid >> 6, lane = tid & 63;
    const int wr = wid / 3, wcn = wid % 3;  // wave grid 4M x 3N; per-wave out 64x64
    const int quad = lane >> 4, l16 = lane & 15;

    // staging roles: waves 0-3 -> B rows (wid*3+j)*16+(lane>>2), j=0..2;
    //                waves 4-11 -> A rows ((wid-4)*2+j)*16+(lane>>2), j=0..1.
    // 16B chunk (lane&3), source pre-swizzled by ((row>>1)&3) == ((lane>>3)&3).
    const bool bstage = (wid < 4);
    const int schunk = (lane & 3) ^ ((lane >> 3) & 3);
    const int srow0 = (bstage ? wid * 48 : (wid - 4) * 32) + (lane >> 2);
    const bf16* gsrc = (bstage ? Bt + (size_t)(n0 + srow0) * 1024
                               : A + (size_t)(m0 + srow0) * 1024) + schunk * 8;
    // LDS dest (elements): A block r at r*512, B block rb at 8192 + rb*512; lane part
    // = lane*8 (16B/lane, exactly the gld_lds linear-dest requirement).
    const int ldst0 = (bstage ? 8192 + wid * 1536 : (wid - 4) * 1024) + lane * 8;

    // read-side swizzled chunk: (row>>1)&3 == (l16>>1)&3 for all fragment rows
    const int coff = ((quad ^ ((l16 >> 1) & 3)) * 8);

    f32x4 acc[4][4] = {};

    auto STAGE = [&](int kt, int p) {
        bf16* d = &LDS[p * 14336 + ldst0];
        const bf16* s = gsrc + kt * 32;
        gld_lds16(s, d);
        gld_lds16(s + (size_t)16 * 1024, d + 512);
        if (bstage) gld_lds16(s + (size_t)32 * 1024, d + 1024);
    };

    STAGE(0, 0);
    STAGE(1, 1);
    if (bstage) VWAIT3(); else VWAIT2();  // drain stage(0); stage(1) stays in flight
    PBAR();

    int rb = 0;   // read buffer for kt
    int sb = 2;   // stage buffer for kt+2
#pragma unroll 1
    for (int kt = 0; kt < 32; kt++) {
        const bf16* Asp = &LDS[rb * 14336];
        const bf16* Bsp = Asp + 8192;
        if (kt + 2 < 32) STAGE(kt + 2, sb);  // buf freed at kt-1's closing barrier

        bf16x8 af[4], bfr[4];
#pragma unroll
        for (int m4 = 0; m4 < 4; m4++)
            af[m4] = *(const bf16x8*)&Asp[(wr * 64 + m4 * 16 + l16) * 32 + coff];
#pragma unroll
        for (int ni = 0; ni < 4; ni++)
            bfr[ni] = *(const bf16x8*)&Bsp[(wcn * 64 + ni * 16 + l16) * 32 + coff];

        __builtin_amdgcn_s_setprio(1);
#pragma unroll
        for (int m4 = 0; m4 < 4; m4++)
#pragma unroll
            for (int ni = 0; ni < 4; ni++)
                acc[m4][ni] = MFMA16(af[m4], bfr[ni], acc[m4][ni]);
        __builtin_amdgcn_s_setprio(0);

        if (kt < 30) {
            if (bstage) VWAIT3(); else VWAIT2();  // drain stage(kt+1) only
            PBAR();
        } else if (kt == 30) {
            VWAIT0();  // last outstanding: STAGE(31)
            PBAR();
        }
        rb = (rb == 2) ? 0 : rb + 1;
        sb = (sb == 2) ? 0 : sb + 1;
    }

    // epilogue: per 16-col fragment, select q/k/v (block may straddle boundaries)
    const int mb0 = m0 + wr * 64;
#pragma unroll
    for (int ni = 0; ni < 4; ni++) {
        const int nlg = n0 + wcn * 64 + ni * 16 + l16;
        const int sel = nlg >> 10;  // wave-uniform per fragment
        const int nl = nlg & 1023;
        if (sel < 2) {
            const float* bias = sel ? b1 : b0;
            bf16* Cp = sel ? kb : qb;
            const float qs = sel ? 1.0f : SM_SCALE;
            const float bv = bias[nl];
#pragma unroll
            for (int mi = 0; mi < 4; mi++) {
                const int mbase = mb0 + mi * 16 + quad * 4;
#pragma unroll
                for (int r = 0; r < 4; r++)
                    Cp[(size_t)(mbase + r) * 1024 + nl] = (bf16)((acc[mi][ni][r] + bv) * qs);
            }
        } else {
            const int h = nl >> 6, d = nl & 63;
            const float bv = b2[nl];
            const int bb = m0 >> 11;  // 256-row block never straddles a batch
            bf16* dst = Vt + ((size_t)(bb * 16 + h) * 64 + d) * 2048;
#pragma unroll
            for (int mi = 0; mi < 4; mi++) {
                const int t0 = (mb0 + mi * 16 + quad * 4) & 2047;  // batch-local t
                bf16x4 w = {(bf16)(acc[mi][ni][0] + bv), (bf16)(acc[mi][ni][1] + bv),
                            (bf16)(acc[mi][ni][2] + bv), (bf16)(acc[mi][ni][3] + bv)};
                *(bf16x4*)&dst[t0] = w;
            }
        }
    }
}

// ---------------- proj GEMM: 256x128 tile, BK=32, 8 waves, 3-buf (R14 MODE-1 path) --------
__global__ __launch_bounds__(512, 4) void gemm_proj(const bf16* __restrict__ A,
                                                    const bf16* __restrict__ Bt,
                                                    const float* __restrict__ b0,
                                                    float* __restrict__ out0,
                                                    int nbx) {
    __shared__ alignas(16) bf16 LDS[3 * 12288];  // per buf: A 256x32 @0 | B 128x32 @8192

    const int orig = blockIdx.x;
    const int chunk = (int)gridDim.x >> 3;
    const int swz = (orig & 7) * chunk + (orig >> 3);
    const int by = swz / nbx, bx = swz % nbx;
    const int m0 = by * 256, n0 = bx * 128;

    const int tid = threadIdx.x;
    const int wid = tid >> 6, lane = tid & 63;
    const int wr = wid >> 1, wc = wid & 1;  // wave grid 4M x 2N; per-wave out 64x64
    const int quad = lane >> 4, l16 = lane & 15;

    const int sr = tid >> 2;
    const int scol = (((tid & 3) ^ ((sr >> 1) & 3)) * 8);
    const bf16* gA = A + (size_t)(m0 + sr) * 1024 + scol;
    const bf16* gB = Bt + (size_t)(n0 + sr) * 1024 + scol;
    bf16* lA = &LDS[tid * 8];
    bf16* lB = &LDS[8192 + tid * 8];

    const int coff = ((quad ^ ((l16 >> 1) & 3)) * 8);

    f32x4 acc[4][4] = {};

    auto STAGE = [&](int kt, int p) {
        const int base = p * 12288;
        gld_lds16(gA + kt * 32, lA + base);
        gld_lds16(gA + kt * 32 + (size_t)128 * 1024, lA + base + 4096);
        gld_lds16(gB + kt * 32, lB + base);
    };

    STAGE(0, 0);
    STAGE(1, 1);
    VWAIT3();
    PBAR();

    int rb = 0, sb = 2;
#pragma unroll 1
    for (int kt = 0; kt < 32; kt++) {
        const bf16* Asp = &LDS[rb * 12288];
        const bf16* Bsp = Asp + 8192;
        if (kt + 2 < 32) STAGE(kt + 2, sb);

        bf16x8 af[4], bfr[4];
#pragma unroll
        for (int m4 = 0; m4 < 4; m4++)
            af[m4] = *(const bf16x8*)&Asp[(wr * 64 + m4 * 16 + l16) * 32 + coff];
#pragma unroll
        for (int ni = 0; ni < 4; ni++)
            bfr[ni] = *(const bf16x8*)&Bsp[(wc * 64 + ni * 16 + l16) * 32 + coff];

        __builtin_amdgcn_s_setprio(1);
#pragma unroll
        for (int m4 = 0; m4 < 4; m4++)
#pragma unroll
            for (int ni = 0; ni < 4; ni++)
                acc[m4][ni] = MFMA16(af[m4], bfr[ni], acc[m4][ni]);
        __builtin_amdgcn_s_setprio(0);

        if (kt < 30) {
            VWAIT3();
            PBAR();
        } else if (kt == 30) {
            VWAIT0();
            PBAR();
        }
        rb = (rb == 2) ? 0 : rb + 1;
        sb = (sb == 2) ? 0 : sb + 1;
    }

    const int mb0 = m0 + wr * 64;
#pragma unroll
    for (int mi = 0; mi < 4; mi++) {
        const int mbase = mb0 + mi * 16 + quad * 4;
#pragma unroll
        for (int ni = 0; ni < 4; ni++) {
            const int n = n0 + wc * 64 + ni * 16 + l16;
            const float bv = b0[n];
#pragma unroll
            for (int r = 0; r < 4; r++)
                out0[(size_t)(mbase + r) * 1024 + n] = acc[mi][ni][r] + bv;
        }
    }
}

// ---------------- flash attention, causal, hs=64 (R15 structure, unchanged) ----------------
template <bool NEEDMASK>
__device__ __forceinline__ void softmax_reg(const f32x4* st, bf16x8* pf, int qrel) {
    unsigned int p[4][2];
#pragma unroll
    for (int j = 0; j < 4; j++) {
        float pv[4];
#pragma unroll
        for (int r = 0; r < 4; r++) {
            float s = st[j][r];
            if (NEEDMASK && (j * 16 + r > qrel)) s = -1e30f;
            pv[r] = __builtin_amdgcn_exp2f(s);
        }
        bf16x2 w0 = {(bf16)pv[0], (bf16)pv[1]};  // v_cvt_pk_bf16_f32 (compiler-fused)
        bf16x2 w1 = {(bf16)pv[2], (bf16)pv[3]};
        p[j][0] = __builtin_bit_cast(unsigned int, w0);
        p[j][1] = __builtin_bit_cast(unsigned int, w1);
    }
    // acc layout -> B-frag layout: permlane32_swap then permlane16_swap (l16 invariant)
#pragma unroll
    for (int ks = 0; ks < 2; ks++) {
        unsigned int q4[4];
#pragma unroll
        for (int h = 0; h < 2; h++) {
            u32x2 s32 = __builtin_amdgcn_permlane32_swap(p[2 * ks][h], p[2 * ks + 1][h],
                                                         false, false);
            u32x2 s16 = __builtin_amdgcn_permlane16_swap(s32[0], s32[1], false, false);
            q4[h] = s16[0];      // e2 = h     (kv ofs 2h, 2h+1)
            q4[2 + h] = s16[1];  // e2 = 2+h   (kv ofs 4+2h, 5+2h)
        }
        u32x4 qq = {q4[0], q4[1], q4[2], q4[3]};
        pf[ks] = __builtin_bit_cast(bf16x8, qq);
    }
}

__global__ __launch_bounds__(256, 2) void attn(const bf16* __restrict__ Q,
                                               const bf16* __restrict__ Kg,
                                               const bf16* __restrict__ Vt,
                                               bf16* __restrict__ O) {
    // bijective XCD swizzle: 512 blocks; lin%8 = XCD -> 8 whole (b,h) heads per XCD.
    const int lin = blockIdx.x;
    const int bh = (lin & 7) * 8 + ((lin >> 3) & 7);
    const int jb = lin >> 6;  // [0,8)
    const int b = bh >> 4, h = bh & 15;
    const int tid = threadIdx.x;
    const int wave = tid >> 6, lane = tid & 63;
    const int quad = lane >> 4, l16 = lane & 15;

    __shared__ alignas(16) bf16 KVs[3 * 8192];  // 3-buf; per buf: K 64x64 | V^T 64x64 (swz)

    const bf16* Kbase = Kg + ((size_t)b * 2048) * 1024 + h * 64;
    const bf16* Vbase = Vt + (size_t)bh * 64 * 2048;

    const int srow = tid >> 3;
    const int schunk = (tid & 7) ^ (srow & 7);

    const int xorE = (l16 & 7) * 8;
    const int cofA = (quad * 8) ^ xorE;       // ks=0
    const int cofB = (32 + quad * 8) ^ xorE;  // ks=1

    const bf16 one1 = (bf16)1.0f;
    const bf16x8 onesf = {one1, one1, one1, one1, one1, one1, one1, one1};

#pragma unroll 1
    for (int phase = 0; phase < 2; phase++) {
        // strip pairing at 128-q granularity: (15-jb) then jb -> 36 tiles total
        const int js = (phase == 0) ? (15 - jb) : jb;
        const int q0 = js * 128;
        const bf16* Qbase = Q + ((size_t)(b * 2048 + q0)) * 1024 + h * 64;

        // Q fragments for both strips (A: rows 0-63, B: rows 64-127 of the q-block)
        bf16x8 qfA[2], qfB[2];
#pragma unroll
        for (int ks = 0; ks < 2; ks++) {
            qfA[ks] = *(const bf16x8*)&Qbase[(size_t)(wave * 16 + l16) * 1024 + ks * 32 + quad * 8];
            qfB[ks] = *(const bf16x8*)&Qbase[(size_t)(64 + wave * 16 + l16) * 1024 + ks * 32 + quad * 8];
        }

        f32x4 otA[4] = {}, otB[4] = {};
        f32x4 laccA = {0.f, 0.f, 0.f, 0.f}, laccB = {0.f, 0.f, 0.f, 0.f};
        const int ntiles = 2 * js + 2;
        const int qrel = wave * 16 + l16 - quad * 4;

        const bf16* pK = Kbase + (size_t)srow * 1024 + schunk * 8;
        const bf16* pK2 = pK + (size_t)32 * 1024;
        const bf16* pV = Vbase + (size_t)srow * 2048 + schunk * 8;
        const bf16* pV2 = pV + (size_t)32 * 2048;

        // prologue: stage tiles 0 and 1 (ntiles >= 2 always)
        {
            bf16* nb = &KVs[tid * 8];
            gld_lds16(pK, nb);
            gld_lds16(pK2, nb + 2048);
            gld_lds16(pV, nb + 4096);
            gld_lds16(pV2, nb + 6144);
            pK += 64 * 1024; pK2 += 64 * 1024; pV += 64; pV2 += 64;
            nb = &KVs[8192 + tid * 8];
            gld_lds16(pK, nb);
            gld_lds16(pK2, nb + 2048);
            gld_lds16(pV, nb + 4096);
            gld_lds16(pV2, nb + 6144);
            pK += 64 * 1024; pK2 += 64 * 1024; pV += 64; pV2 += 64;
        }
        VWAIT4();  // drain stage(0); stage(1) stays in flight
        PBAR();

        int rbuf = 0, sbuf = 2;
#pragma unroll 1
        for (int tk = 0; tk < ntiles; tk++) {
            const bf16* buf = &KVs[rbuf * 8192];
            if (tk + 2 < ntiles) {  // stage(t+2): drained at t+1's end (2 bodies away)
                bf16* nb = &KVs[sbuf * 8192 + tid * 8];
                gld_lds16(pK, nb);
                gld_lds16(pK2, nb + 2048);
                gld_lds16(pV, nb + 4096);
                gld_lds16(pV2, nb + 6144);
                pK += 64 * 1024; pK2 += 64 * 1024; pV += 64; pV2 += 64;
            }

            // S^T = K . Q^T for both strips; each kf read feeds 2 MFMAs
            f32x4 stA[4] = {}, stB[4] = {};
#pragma unroll
            for (int ks = 0; ks < 2; ks++)
#pragma unroll
                for (int j = 0; j < 4; j++) {
                    const bf16x8 kf =
                        *(const bf16x8*)&buf[(j * 16 + l16) * 64 + (ks ? cofB : cofA)];
                    stA[j] = MFMA16(kf, qfA[ks], stA[j]);
                    stB[j] = MFMA16(kf, qfB[ks], stB[j]);
                }

            // softmax per strip (A's diagonal at ntiles-2; B's at ntiles-1, where A is
            // fully masked via qrel-64 -> pfA = 0)
            bf16x8 pfA[2], pfB[2];
            if (tk < ntiles - 2) {
                softmax_reg<false>(stA, pfA, qrel);
                softmax_reg<false>(stB, pfB, qrel);
            } else if (tk == ntiles - 2) {
                softmax_reg<true>(stA, pfA, qrel);
                softmax_reg<false>(stB, pfB, qrel);
            } else {
                softmax_reg<true>(stA, pfA, qrel - 64);
                softmax_reg<true>(stB, pfB, qrel);
            }

            // l-sums via MFMA ones-fragment
            laccA = MFMA16(onesf, pfA[0], laccA);
            laccA = MFMA16(onesf, pfA[1], laccA);
            laccB = MFMA16(onesf, pfB[0], laccB);
            laccB = MFMA16(onesf, pfB[1], laccB);

            // O^T += V^T . P^T; each vf read feeds 2 MFMAs
#pragma unroll
            for (int ks = 0; ks < 2; ks++)
#pragma unroll
                for (int db = 0; db < 4; db++) {
                    const bf16x8 vf = *(const bf16x8*)&buf[4096 + (db * 16 + l16) * 64 +
                                                           (ks ? cofB : cofA)];
                    otA[db] = MFMA16(vf, pfA[ks], otA[db]);
                    otB[db] = MFMA16(vf, pfB[ks], otB[db]);
                }

            if (tk + 1 < ntiles) {
                if (tk + 2 < ntiles) VWAIT4();  // drain stage(t+1); stage(t+2) in flight
                else VWAIT0();                  // tail: drain the last stage
                PBAR();                         // publish t+1; buf[rbuf] readers done
            }
            rbuf = (rbuf == 2) ? 0 : rbuf + 1;
            sbuf = (sbuf == 2) ? 0 : sbuf + 1;
        }

        // epilogue: per strip, O^T regs -> transpose scratch in buf[(ntiles+1)%3]
        // (no pending gld_lds; its readers done). Strips sequential through the same
        // per-wave 16x72 region (same-wave LDS ops are in-order -> WAR safe).
        bf16* ep = &KVs[((ntiles + 1) % 3) * 8192 + wave * (16 * 72)];
        const int orow = lane >> 2, oc = (lane & 3) * 16;
        {
            const float inv = 1.f / laccA[0];
#pragma unroll
            for (int db = 0; db < 4; db++) {
                bf16x4 w = {(bf16)(otA[db][0] * inv), (bf16)(otA[db][1] * inv),
                            (bf16)(otA[db][2] * inv), (bf16)(otA[db][3] * inv)};
                *(bf16x4*)&ep[l16 * 72 + db * 16 + quad * 4] = w;
            }
            bf16* Obase =
                O + ((size_t)(b * 2048 + q0 + wave * 16 + orow)) * 1024 + h * 64 + oc;
            const bf16* src = &ep[orow * 72 + oc];
            *(bf16x8*)&Obase[0] = *(const bf16x8*)&src[0];
            *(bf16x8*)&Obase[8] = *(const bf16x8*)&src[8];
        }
        {
            const float inv = 1.f / laccB[0];
#pragma unroll
            for (int db = 0; db < 4; db++) {
                bf16x4 w = {(bf16)(otB[db][0] * inv), (bf16)(otB[db][1] * inv),
                            (bf16)(otB[db][2] * inv), (bf16)(otB[db][3] * inv)};
                *(bf16x4*)&ep[l16 * 72 + db * 16 + quad * 4] = w;
            }
            bf16* Obase =
                O + ((size_t)(b * 2048 + q0 + 64 + wave * 16 + orow)) * 1024 + h * 64 + oc;
            const bf16* src = &ep[orow * 72 + oc];
            *(bf16x8*)&Obase[0] = *(const bf16x8*)&src[0];
            *(bf16x8*)&Obase[8] = *(const bf16x8*)&src[8];
        }
        __syncthreads();  // all buffers drained + epilogue reads done before next phase
    }
}

extern "C" void kernel_launch(void* const* d_in, const int* in_sizes, int n_in,
                              void* d_out, int out_size, void* d_ws, size_t ws_size,
                              hipStream_t stream) {
    const float* x = (const float*)d_in[0];
    const float* Wq = (const float*)d_in[1];
    const float* bq = (const float*)d_in[2];
    const float* Wk = (const float*)d_in[3];
    const float* bk = (const float*)d_in[4];
    const float* Wv = (const float*)d_in[5];
    const float* bv = (const float*)d_in[6];
    float* out = (float*)d_out;

    const int M = 8192;  // B*T
    const size_t sz_x = (size_t)M * 1024;
    const size_t sz_w = (size_t)1024 * 1024;

    char* p = (char*)d_ws;
    bf16* xb = (bf16*)p;   p += sz_x * 2;
    bf16* Wcat = (bf16*)p; p += 3 * sz_w * 2;  // [Wq^T ; Wk^T ; Wv^T]
    bf16* qb = (bf16*)p;   p += sz_x * 2;
    bf16* kb = (bf16*)p;   p += sz_x * 2;
    bf16* Vt = (bf16*)p;   p += sz_x * 2;  // [B*H][64][2048]
    bf16* yatt = (bf16*)p; p += sz_x * 2;

    // W transpose + x convert in one launch
    prep<<<dim3(2816), dim3(256), 0, stream>>>(Wq, Wk, Wv, Wcat, x, xb);

    // fused QKV projection: [8192,1024] @ [1024,3072] -- 256x192, 12 waves, grid 512
    gemm_qkv<<<dim3(512), dim3(768), 0, stream>>>(xb, Wcat, bq, bk, bv, qb, kb, Vt);
    attn<<<dim3(512), dim3(256), 0, stream>>>(qb, kb, Vt, yatt);
    // output projection (reference reuses v_proj): BM=256/BN=128, grid 256
    gemm_proj<<<dim3(256), dim3(512), 0, stream>>>(yatt, Wcat + 2 * sz_w, bv, out, 8);
}

// Round 10
// 222.866 us; speedup vs baseline: 1.0353x; 1.0353x over previous
//
#include <hip/hip_runtime.h>
#include <hip/hip_bf16.h>

typedef __bf16 bf16;
typedef __attribute__((ext_vector_type(8))) __bf16 bf16x8;
typedef __attribute__((ext_vector_type(4))) __bf16 bf16x4;
typedef __attribute__((ext_vector_type(2))) __bf16 bf16x2;
typedef __attribute__((ext_vector_type(4))) float f32x4;
typedef __attribute__((ext_vector_type(2))) unsigned int u32x2;
typedef __attribute__((ext_vector_type(4))) unsigned int u32x4;

#define MFMA16(a, b, c) __builtin_amdgcn_mfma_f32_16x16x32_bf16((a), (b), (c), 0, 0, 0)
#define SM_SCALE 0.18033688011112043f  // (1/8) * log2(e), folded into q at GEMM epilogue

__device__ __forceinline__ void gld_lds16(const bf16* g, bf16* l) {
    __builtin_amdgcn_global_load_lds((const __attribute__((address_space(1))) void*)g,
                                     (__attribute__((address_space(3))) void*)l, 16, 0, 0);
}

// raw barriers: no compiler-inserted vmcnt(0)/lgkmcnt(0) drain at each barrier.
#define PBAR() asm volatile("s_barrier" ::: "memory")
#define VWAIT0() asm volatile("s_waitcnt vmcnt(0)" ::: "memory")
#define VWAIT3() asm volatile("s_waitcnt vmcnt(3)" ::: "memory")
#define VWAIT4() asm volatile("s_waitcnt vmcnt(4)" ::: "memory")

// ---------------- prep: W transpose (blocks 0..767) + x f32->bf16 (blocks 768..2815) --------
__global__ __launch_bounds__(256) void prep(const float* __restrict__ W0,
                                            const float* __restrict__ W1,
                                            const float* __restrict__ W2,
                                            bf16* __restrict__ Wt,
                                            const float* __restrict__ xin,
                                            bf16* __restrict__ xout) {
    __shared__ float tile[64][65];
    const int blk = blockIdx.x;
    const int tid = threadIdx.x;
    if (blk < 768) {
        const int z = blk >> 8, rem = blk & 255;
        const int r0 = (rem >> 4) * 64;  // k
        const int c0 = (rem & 15) * 64;  // n
        const float* W = (z == 0) ? W0 : ((z == 1) ? W1 : W2);
        bf16* dst = Wt + (size_t)z * 1024 * 1024;
        for (int i = tid; i < 4096; i += 256) {
            int r = i >> 6, cc = i & 63;
            tile[r][cc] = W[(size_t)(r0 + r) * 1024 + c0 + cc];
        }
        __syncthreads();
        for (int i = tid; i < 4096; i += 256) {
            int n = i >> 6, k = i & 63;
            dst[(size_t)(c0 + n) * 1024 + r0 + k] = (bf16)tile[k][n];
        }
    } else {
        // 2048 blocks x 256 threads x 16 floats = 8,388,608 = 8192*1024 exactly
        const size_t i0 = ((size_t)(blk - 768) * 256 + tid) * 16;
#pragma unroll
        for (int j = 0; j < 2; j++) {
            const float4 v0 = *(const float4*)(xin + i0 + j * 8);
            const float4 v1 = *(const float4*)(xin + i0 + j * 8 + 4);
            bf16x8 o = {(bf16)v0.x, (bf16)v0.y, (bf16)v0.z, (bf16)v0.w,
                        (bf16)v1.x, (bf16)v1.y, (bf16)v1.z, (bf16)v1.w};
            *(bf16x8*)(xout + i0 + j * 8) = o;
        }
    }
}

// ---------------- GEMM: 256x128 tile, BK=32, 8 waves (4Mx2N), 64x64/wave, 3-buf ----------------
// R14 config (best measured: 63us, MfmaUtil 34%, conflicts 0): prefetch-depth-2, counted
// vmcnt(3), conflict-free ((row>>1)&3) XOR swizzle, 2 blocks/CU resident.
// R16's 1-block/CU regeometry REVERTED: single-block barrier lockstep serializes the LDS
// and MFMA pipes chip-wide; 2 co-resident blocks provide the cross-block phase overlap.
template <int MODE>
__global__ __launch_bounds__(512, 4) void gemm_main(const bf16* __restrict__ A,
                                                    const bf16* __restrict__ Bt,
                                                    const float* __restrict__ b0,
                                                    const float* __restrict__ b1,
                                                    const float* __restrict__ b2,
                                                    void* __restrict__ out0,
                                                    void* __restrict__ out1,
                                                    void* __restrict__ out2,
                                                    int nbx) {
    __shared__ alignas(16) bf16 LDS[3 * 12288];  // per buf: A 256x32 @0 | B 128x32 @8192

    // XCD-chunked bijective swizzle (grid % 8 == 0): contiguous work chunk per XCD.
    const int orig = blockIdx.x;
    const int chunk = (int)gridDim.x >> 3;
    const int swz = (orig & 7) * chunk + (orig >> 3);
    const int by = swz / nbx, bx = swz % nbx;
    const int m0 = by * 256, n0 = bx * 128;

    const int tid = threadIdx.x;
    const int wid = tid >> 6, lane = tid & 63;
    const int wr = wid >> 1, wc = wid & 1;  // wave grid 4M x 2N; per-wave out 64x64
    const int quad = lane >> 4, l16 = lane & 15;

    // staging: thread t covers A rows (t>>2, 128+(t>>2)) and B row (t>>2), 16B chunk
    // (t&3); source chunk pre-swizzled by ((row>>1)&3) so linear LDS + XOR read matches
    // (2-way-only bank aliasing within each 16-lane ds_read phase -> 0 conflicts).
    const int sr = tid >> 2;
    const int scol = (((tid & 3) ^ ((sr >> 1) & 3)) * 8);
    const bf16* gA = A + (size_t)(m0 + sr) * 1024 + scol;
    const bf16* gB = Bt + (size_t)(n0 + sr) * 1024 + scol;
    bf16* lA = &LDS[tid * 8];
    bf16* lB = &LDS[8192 + tid * 8];

    // read-side swizzled chunk: (row>>1)&3 == (l16>>1)&3 for all fragment rows
    const int coff = ((quad ^ ((l16 >> 1) & 3)) * 8);

    f32x4 acc[4][4] = {};

    auto STAGE = [&](int kt, int p) {
        const int base = p * 12288;
        gld_lds16(gA + kt * 32, lA + base);
        gld_lds16(gA + kt * 32 + (size_t)128 * 1024, lA + base + 4096);
        gld_lds16(gB + kt * 32, lB + base);
    };

    STAGE(0, 0);
    STAGE(1, 1);
    VWAIT3();  // drain STAGE(0); STAGE(1) stays in flight
    PBAR();

    int rb = 0;   // read buffer for kt
    int sb = 2;   // stage buffer for kt+2
#pragma unroll 1
    for (int kt = 0; kt < 32; kt++) {
        const bf16* Asp = &LDS[rb * 12288];
        const bf16* Bsp = Asp + 8192;
        if (kt + 2 < 32) STAGE(kt + 2, sb);  // buf freed at kt-1's closing barrier

        bf16x8 af[4], bfr[4];
#pragma unroll
        for (int m4 = 0; m4 < 4; m4++)
            af[m4] = *(const bf16x8*)&Asp[(wr * 64 + m4 * 16 + l16) * 32 + coff];
#pragma unroll
        for (int ni = 0; ni < 4; ni++)
            bfr[ni] = *(const bf16x8*)&Bsp[(wc * 64 + ni * 16 + l16) * 32 + coff];

        __builtin_amdgcn_s_setprio(1);
#pragma unroll
        for (int m4 = 0; m4 < 4; m4++)
#pragma unroll
            for (int ni = 0; ni < 4; ni++)
                acc[m4][ni] = MFMA16(af[m4], bfr[ni], acc[m4][ni]);
        __builtin_amdgcn_s_setprio(0);

        if (kt < 30) {
            VWAIT3();  // drain stage(kt+1) only; stage(kt+2) flies across the barrier
            PBAR();
        } else if (kt == 30) {
            VWAIT0();  // last outstanding: STAGE(31)
            PBAR();
        }
        rb = (rb == 2) ? 0 : rb + 1;
        sb = (sb == 2) ? 0 : sb + 1;
    }

    // epilogue
    const int nl0 = (n0 & 1023) + wc * 64;
    const int mb0 = m0 + wr * 64;
    if (MODE == 0) {
        const int sel = n0 >> 10;  // 0=q, 1=k, 2=v  (128 | 1024 -> never straddles)
        if (sel < 2) {
            const float* bias = (sel == 0) ? b0 : b1;
            bf16* Cp = (bf16*)((sel == 0) ? out0 : out1);
            const float qs = (sel == 0) ? SM_SCALE : 1.0f;
#pragma unroll
            for (int mi = 0; mi < 4; mi++) {
                const int mbase = mb0 + mi * 16 + quad * 4;
#pragma unroll
                for (int ni = 0; ni < 4; ni++) {
                    const int nl = nl0 + ni * 16 + l16;
                    const float bv = bias[nl];
#pragma unroll
                    for (int r = 0; r < 4; r++)
                        Cp[(size_t)(mbase + r) * 1024 + nl] =
                            (bf16)((acc[mi][ni][r] + bv) * qs);
                }
            }
        } else {
            bf16* Vt = (bf16*)out2;
            const int b = m0 >> 11;  // 2048 rows/batch; 256-row block never straddles
#pragma unroll
            for (int ni = 0; ni < 4; ni++) {
                const int nl = nl0 + ni * 16 + l16;
                const int h = nl >> 6, d = nl & 63;
                const float bv = b2[nl];
                bf16* dst = Vt + ((size_t)(b * 16 + h) * 64 + d) * 2048;
#pragma unroll
                for (int mi = 0; mi < 4; mi++) {
                    const int t0 = (mb0 + mi * 16 + quad * 4) & 2047;  // batch-local t
                    bf16x4 w = {(bf16)(acc[mi][ni][0] + bv), (bf16)(acc[mi][ni][1] + bv),
                                (bf16)(acc[mi][ni][2] + bv), (bf16)(acc[mi][ni][3] + bv)};
                    *(bf16x4*)&dst[t0] = w;
                }
            }
        }
    } else {
        float* Cp = (float*)out0;
#pragma unroll
        for (int mi = 0; mi < 4; mi++) {
            const int mbase = mb0 + mi * 16 + quad * 4;
#pragma unroll
            for (int ni = 0; ni < 4; ni++) {
                const int n = n0 + wc * 64 + ni * 16 + l16;
                const float bv = b0[n];
#pragma unroll
                for (int r = 0; r < 4; r++)
                    Cp[(size_t)(mbase + r) * 1024 + n] = acc[mi][ni][r] + bv;
            }
        }
    }
}

// ---------------- flash attention, causal, hs=64 ----------------
// R17 vs R15: (1) T5 setprio(1) around QK and PV MFMA clusters (2 independent blocks/CU,
// waves drift -> the regime where setprio measured +4-7%); (2) final tile peeled: strip A
// is fully masked there (qrel-64 < 0 -> pfA == 0), so its QK/softmax/l/PV all produce
// exact zeros -- skipped entirely, and the mask branch leaves the hot loop.
template <bool NEEDMASK>
__device__ __forceinline__ void softmax_reg(const f32x4* st, bf16x8* pf, int qrel) {
    unsigned int p[4][2];
#pragma unroll
    for (int j = 0; j < 4; j++) {
        float pv[4];
#pragma unroll
        for (int r = 0; r < 4; r++) {
            float s = st[j][r];
            if (NEEDMASK && (j * 16 + r > qrel)) s = -1e30f;
            pv[r] = __builtin_amdgcn_exp2f(s);
        }
        bf16x2 w0 = {(bf16)pv[0], (bf16)pv[1]};  // v_cvt_pk_bf16_f32 (compiler-fused)
        bf16x2 w1 = {(bf16)pv[2], (bf16)pv[3]};
        p[j][0] = __builtin_bit_cast(unsigned int, w0);
        p[j][1] = __builtin_bit_cast(unsigned int, w1);
    }
    // acc layout -> B-frag layout: permlane32_swap then permlane16_swap (l16 invariant)
#pragma unroll
    for (int ks = 0; ks < 2; ks++) {
        unsigned int q4[4];
#pragma unroll
        for (int h = 0; h < 2; h++) {
            u32x2 s32 = __builtin_amdgcn_permlane32_swap(p[2 * ks][h], p[2 * ks + 1][h],
                                                         false, false);
            u32x2 s16 = __builtin_amdgcn_permlane16_swap(s32[0], s32[1], false, false);
            q4[h] = s16[0];      // e2 = h     (kv ofs 2h, 2h+1)
            q4[2 + h] = s16[1];  // e2 = 2+h   (kv ofs 4+2h, 5+2h)
        }
        u32x4 qq = {q4[0], q4[1], q4[2], q4[3]};
        pf[ks] = __builtin_bit_cast(bf16x8, qq);
    }
}

__global__ __launch_bounds__(256, 2) void attn(const bf16* __restrict__ Q,
                                               const bf16* __restrict__ Kg,
                                               const bf16* __restrict__ Vt,
                                               bf16* __restrict__ O) {
    // bijective XCD swizzle: 512 blocks; lin%8 = XCD -> 8 whole (b,h) heads per XCD.
    const int lin = blockIdx.x;
    const int bh = (lin & 7) * 8 + ((lin >> 3) & 7);
    const int jb = lin >> 6;  // [0,8)
    const int b = bh >> 4, h = bh & 15;
    const int tid = threadIdx.x;
    const int wave = tid >> 6, lane = tid & 63;
    const int quad = lane >> 4, l16 = lane & 15;

    __shared__ alignas(16) bf16 KVs[3 * 8192];  // 3-buf; per buf: K 64x64 | V^T 64x64 (swz)

    const bf16* Kbase = Kg + ((size_t)b * 2048) * 1024 + h * 64;
    const bf16* Vbase = Vt + (size_t)bh * 64 * 2048;

    const int srow = tid >> 3;
    const int schunk = (tid & 7) ^ (srow & 7);

    const int xorE = (l16 & 7) * 8;
    const int cofA = (quad * 8) ^ xorE;       // ks=0
    const int cofB = (32 + quad * 8) ^ xorE;  // ks=1

    const bf16 one1 = (bf16)1.0f;
    const bf16x8 onesf = {one1, one1, one1, one1, one1, one1, one1, one1};

#pragma unroll 1
    for (int phase = 0; phase < 2; phase++) {
        // strip pairing at 128-q granularity: (15-jb) then jb -> 36 tiles total
        const int js = (phase == 0) ? (15 - jb) : jb;
        const int q0 = js * 128;
        const bf16* Qbase = Q + ((size_t)(b * 2048 + q0)) * 1024 + h * 64;

        // Q fragments for both strips (A: rows 0-63, B: rows 64-127 of the q-block)
        bf16x8 qfA[2], qfB[2];
#pragma unroll
        for (int ks = 0; ks < 2; ks++) {
            qfA[ks] = *(const bf16x8*)&Qbase[(size_t)(wave * 16 + l16) * 1024 + ks * 32 + quad * 8];
            qfB[ks] = *(const bf16x8*)&Qbase[(size_t)(64 + wave * 16 + l16) * 1024 + ks * 32 + quad * 8];
        }

        f32x4 otA[4] = {}, otB[4] = {};
        f32x4 laccA = {0.f, 0.f, 0.f, 0.f}, laccB = {0.f, 0.f, 0.f, 0.f};
        const int ntiles = 2 * js + 2;
        const int qrel = wave * 16 + l16 - quad * 4;

        const bf16* pK = Kbase + (size_t)srow * 1024 + schunk * 8;
        const bf16* pK2 = pK + (size_t)32 * 1024;
        const bf16* pV = Vbase + (size_t)srow * 2048 + schunk * 8;
        const bf16* pV2 = pV + (size_t)32 * 2048;

        // prologue: stage tiles 0 and 1 (ntiles >= 2 always)
        {
            bf16* nb = &KVs[tid * 8];
            gld_lds16(pK, nb);
            gld_lds16(pK2, nb + 2048);
            gld_lds16(pV, nb + 4096);
            gld_lds16(pV2, nb + 6144);
            pK += 64 * 1024; pK2 += 64 * 1024; pV += 64; pV2 += 64;
            nb = &KVs[8192 + tid * 8];
            gld_lds16(pK, nb);
            gld_lds16(pK2, nb + 2048);
            gld_lds16(pV, nb + 4096);
            gld_lds16(pV2, nb + 6144);
            pK += 64 * 1024; pK2 += 64 * 1024; pV += 64; pV2 += 64;
        }
        VWAIT4();  // drain stage(0); stage(1) stays in flight
        PBAR();

        int rbuf = 0, sbuf = 2;
#pragma unroll 1
        for (int tk = 0; tk < ntiles - 1; tk++) {
            const bf16* buf = &KVs[rbuf * 8192];
            if (tk + 2 < ntiles) {  // stage(t+2): drained at t+1's end (2 bodies away)
                bf16* nb = &KVs[sbuf * 8192 + tid * 8];
                gld_lds16(pK, nb);
                gld_lds16(pK2, nb + 2048);
                gld_lds16(pV, nb + 4096);
                gld_lds16(pV2, nb + 6144);
                pK += 64 * 1024; pK2 += 64 * 1024; pV += 64; pV2 += 64;
            }

            // S^T = K . Q^T for both strips; each kf read feeds 2 MFMAs
            f32x4 stA[4] = {}, stB[4] = {};
            __builtin_amdgcn_s_setprio(1);
#pragma unroll
            for (int ks = 0; ks < 2; ks++)
#pragma unroll
                for (int j = 0; j < 4; j++) {
                    const bf16x8 kf =
                        *(const bf16x8*)&buf[(j * 16 + l16) * 64 + (ks ? cofB : cofA)];
                    stA[j] = MFMA16(kf, qfA[ks], stA[j]);
                    stB[j] = MFMA16(kf, qfB[ks], stB[j]);
                }
            __builtin_amdgcn_s_setprio(0);

            // softmax per strip (A's diagonal at ntiles-2; B unmasked in-loop)
            bf16x8 pfA[2], pfB[2];
            if (tk == ntiles - 2) {
                softmax_reg<true>(stA, pfA, qrel);
                softmax_reg<false>(stB, pfB, qrel);
            } else {
                softmax_reg<false>(stA, pfA, qrel);
                softmax_reg<false>(stB, pfB, qrel);
            }

            // l-sums via MFMA ones-fragment
            laccA = MFMA16(onesf, pfA[0], laccA);
            laccA = MFMA16(onesf, pfA[1], laccA);
            laccB = MFMA16(onesf, pfB[0], laccB);
            laccB = MFMA16(onesf, pfB[1], laccB);

            // O^T += V^T . P^T; each vf read feeds 2 MFMAs
            __builtin_amdgcn_s_setprio(1);
#pragma unroll
            for (int ks = 0; ks < 2; ks++)
#pragma unroll
                for (int db = 0; db < 4; db++) {
                    const bf16x8 vf = *(const bf16x8*)&buf[4096 + (db * 16 + l16) * 64 +
                                                           (ks ? cofB : cofA)];
                    otA[db] = MFMA16(vf, pfA[ks], otA[db]);
                    otB[db] = MFMA16(vf, pfB[ks], otB[db]);
                }
            __builtin_amdgcn_s_setprio(0);

            if (tk + 2 < ntiles) VWAIT4();  // drain stage(t+1); stage(t+2) in flight
            else VWAIT0();                  // tail: drain the last stage
            PBAR();                         // publish t+1; buf[rbuf] readers done
            rbuf = (rbuf == 2) ? 0 : rbuf + 1;
            sbuf = (sbuf == 2) ? 0 : sbuf + 1;
        }

        // peeled final tile: strip B's diagonal. Strip A fully masked here (qrel-64 < 0
        // -> pfA == 0): its QK/softmax/l/PV all contribute zeros -> skipped entirely.
        {
            const bf16* buf = &KVs[rbuf * 8192];
            f32x4 stB[4] = {};
            __builtin_amdgcn_s_setprio(1);
#pragma unroll
            for (int ks = 0; ks < 2; ks++)
#pragma unroll
                for (int j = 0; j < 4; j++) {
                    const bf16x8 kf =
                        *(const bf16x8*)&buf[(j * 16 + l16) * 64 + (ks ? cofB : cofA)];
                    stB[j] = MFMA16(kf, qfB[ks], stB[j]);
                }
            __builtin_amdgcn_s_setprio(0);
            bf16x8 pfB[2];
            softmax_reg<true>(stB, pfB, qrel);
            laccB = MFMA16(onesf, pfB[0], laccB);
            laccB = MFMA16(onesf, pfB[1], laccB);
            __builtin_amdgcn_s_setprio(1);
#pragma unroll
            for (int ks = 0; ks < 2; ks++)
#pragma unroll
                for (int db = 0; db < 4; db++) {
                    const bf16x8 vf = *(const bf16x8*)&buf[4096 + (db * 16 + l16) * 64 +
                                                           (ks ? cofB : cofA)];
                    otB[db] = MFMA16(vf, pfB[ks], otB[db]);
                }
            __builtin_amdgcn_s_setprio(0);
        }

        // epilogue: per strip, O^T regs -> transpose scratch in buf[(ntiles+1)%3]
        // (!= peeled tile's buffer; its prior readers finished at the last in-loop
        // barrier). Strips sequential through the same per-wave 16x72 region
        // (same-wave LDS ops are in-order -> WAR safe).
        bf16* ep = &KVs[((ntiles + 1) % 3) * 8192 + wave * (16 * 72)];
        const int orow = lane >> 2, oc = (lane & 3) * 16;
        {
            const float inv = 1.f / laccA[0];
#pragma unroll
            for (int db = 0; db < 4; db++) {
                bf16x4 w = {(bf16)(otA[db][0] * inv), (bf16)(otA[db][1] * inv),
                            (bf16)(otA[db][2] * inv), (bf16)(otA[db][3] * inv)};
                *(bf16x4*)&ep[l16 * 72 + db * 16 + quad * 4] = w;
            }
            bf16* Obase =
                O + ((size_t)(b * 2048 + q0 + wave * 16 + orow)) * 1024 + h * 64 + oc;
            const bf16* src = &ep[orow * 72 + oc];
            *(bf16x8*)&Obase[0] = *(const bf16x8*)&src[0];
            *(bf16x8*)&Obase[8] = *(const bf16x8*)&src[8];
        }
        {
            const float inv = 1.f / laccB[0];
#pragma unroll
            for (int db = 0; db < 4; db++) {
                bf16x4 w = {(bf16)(otB[db][0] * inv), (bf16)(otB[db][1] * inv),
                            (bf16)(otB[db][2] * inv), (bf16)(otB[db][3] * inv)};
                *(bf16x4*)&ep[l16 * 72 + db * 16 + quad * 4] = w;
            }
            bf16* Obase =
                O + ((size_t)(b * 2048 + q0 + 64 + wave * 16 + orow)) * 1024 + h * 64 + oc;
            const bf16* src = &ep[orow * 72 + oc];
            *(bf16x8*)&Obase[0] = *(const bf16x8*)&src[0];
            *(bf16x8*)&Obase[8] = *(const bf16x8*)&src[8];
        }
        __syncthreads();  // all buffers drained + epilogue reads done before next phase
    }
}

extern "C" void kernel_launch(void* const* d_in, const int* in_sizes, int n_in,
                              void* d_out, int out_size, void* d_ws, size_t ws_size,
                              hipStream_t stream) {
    const float* x = (const float*)d_in[0];
    const float* Wq = (const float*)d_in[1];
    const float* bq = (const float*)d_in[2];
    const float* Wk = (const float*)d_in[3];
    const float* bk = (const float*)d_in[4];
    const float* Wv = (const float*)d_in[5];
    const float* bv = (const float*)d_in[6];
    float* out = (float*)d_out;

    const int M = 8192;  // B*T
    const size_t sz_x = (size_t)M * 1024;
    const size_t sz_w = (size_t)1024 * 1024;

    char* p = (char*)d_ws;
    bf16* xb = (bf16*)p;   p += sz_x * 2;
    bf16* Wcat = (bf16*)p; p += 3 * sz_w * 2;  // [Wq^T ; Wk^T ; Wv^T]
    bf16* qb = (bf16*)p;   p += sz_x * 2;
    bf16* kb = (bf16*)p;   p += sz_x * 2;
    bf16* Vt = (bf16*)p;   p += sz_x * 2;  // [B*H][64][2048]
    bf16* yatt = (bf16*)p; p += sz_x * 2;

    // W transpose + x convert in one launch
    prep<<<dim3(2816), dim3(256), 0, stream>>>(Wq, Wk, Wv, Wcat, x, xb);

    // fused QKV projection: [8192,1024] @ [1024,3072] -- 256x128/BK32, 3-buf depth-2
    gemm_main<0><<<dim3(768), dim3(512), 0, stream>>>(xb, Wcat, bq, bk, bv, qb, kb, Vt, 24);
    attn<<<dim3(512), dim3(256), 0, stream>>>(qb, kb, Vt, yatt);
    // output projection (reference reuses v_proj): BM=256, grid 256
    gemm_main<1><<<dim3(256), dim3(512), 0, stream>>>(yatt, Wcat + 2 * sz_w, bv, bv, bv,
                                                      out, out, out, 8);
}

// Round 11
// 221.439 us; speedup vs baseline: 1.0419x; 1.0064x over previous
//
#include <hip/hip_runtime.h>
#include <hip/hip_bf16.h>

typedef __bf16 bf16;
typedef __attribute__((ext_vector_type(8))) __bf16 bf16x8;
typedef __attribute__((ext_vector_type(4))) __bf16 bf16x4;
typedef __attribute__((ext_vector_type(2))) __bf16 bf16x2;
typedef __attribute__((ext_vector_type(4))) float f32x4;
typedef __attribute__((ext_vector_type(2))) unsigned int u32x2;
typedef __attribute__((ext_vector_type(4))) unsigned int u32x4;

#define MFMA16(a, b, c) __builtin_amdgcn_mfma_f32_16x16x32_bf16((a), (b), (c), 0, 0, 0)
#define SM_SCALE 0.18033688011112043f  // (1/8) * log2(e), folded into q at GEMM epilogue

__device__ __forceinline__ void gld_lds16(const bf16* g, bf16* l) {
    __builtin_amdgcn_global_load_lds((const __attribute__((address_space(1))) void*)g,
                                     (__attribute__((address_space(3))) void*)l, 16, 0, 0);
}

// raw barriers: no compiler-inserted vmcnt(0)/lgkmcnt(0) drain at each barrier.
#define PBAR() asm volatile("s_barrier" ::: "memory")
#define VWAIT0() asm volatile("s_waitcnt vmcnt(0)" ::: "memory")
#define VWAIT3() asm volatile("s_waitcnt vmcnt(3)" ::: "memory")
#define VWAIT4() asm volatile("s_waitcnt vmcnt(4)" ::: "memory")
#define VWAIT6() asm volatile("s_waitcnt vmcnt(6)" ::: "memory")

// ---------------- prep: W transpose (blocks 0..767) + x f32->bf16 (blocks 768..2815) --------
__global__ __launch_bounds__(256) void prep(const float* __restrict__ W0,
                                            const float* __restrict__ W1,
                                            const float* __restrict__ W2,
                                            bf16* __restrict__ Wt,
                                            const float* __restrict__ xin,
                                            bf16* __restrict__ xout) {
    __shared__ float tile[64][65];
    const int blk = blockIdx.x;
    const int tid = threadIdx.x;
    if (blk < 768) {
        const int z = blk >> 8, rem = blk & 255;
        const int r0 = (rem >> 4) * 64;  // k
        const int c0 = (rem & 15) * 64;  // n
        const float* W = (z == 0) ? W0 : ((z == 1) ? W1 : W2);
        bf16* dst = Wt + (size_t)z * 1024 * 1024;
        for (int i = tid; i < 4096; i += 256) {
            int r = i >> 6, cc = i & 63;
            tile[r][cc] = W[(size_t)(r0 + r) * 1024 + c0 + cc];
        }
        __syncthreads();
        for (int i = tid; i < 4096; i += 256) {
            int n = i >> 6, k = i & 63;
            dst[(size_t)(c0 + n) * 1024 + r0 + k] = (bf16)tile[k][n];
        }
    } else {
        // 2048 blocks x 256 threads x 16 floats = 8,388,608 = 8192*1024 exactly
        const size_t i0 = ((size_t)(blk - 768) * 256 + tid) * 16;
#pragma unroll
        for (int j = 0; j < 2; j++) {
            const float4 v0 = *(const float4*)(xin + i0 + j * 8);
            const float4 v1 = *(const float4*)(xin + i0 + j * 8 + 4);
            bf16x8 o = {(bf16)v0.x, (bf16)v0.y, (bf16)v0.z, (bf16)v0.w,
                        (bf16)v1.x, (bf16)v1.y, (bf16)v1.z, (bf16)v1.w};
            *(bf16x8*)(xout + i0 + j * 8) = o;
        }
    }
}

// ---------------- QKV GEMM: 256x128 tile, BK=32, 4 waves, 64x128/wave, 3-buf ----------------
// R18: fragment-reuse regeometry on the proven R14 pipeline. Per-wave output 64x128:
// 12 ds_read_b128 feed 32 MFMA (0.375 reads/MFMA, was 0.5). Per CU per K-step: LDS
// 8 waves x 12KB reads + 24KB x 2 writes ~= 1143cy < MFMA 1241cy -> MFMA-dominant.
// Same 3-buf depth-2 counted-vmcnt pipeline, same ((row>>1)&3) involution swizzle
// (bank-exact same as R14's zero-conflict config), same grid 768 @ 2 blocks/CU
// (LDS 72KB identical; acc 128 AGPR + ~100 VGPR -> 2 waves/SIMD = the 8 resident waves).
__global__ __launch_bounds__(256, 2) void gemm_qkv(const bf16* __restrict__ A,
                                                   const bf16* __restrict__ Bt,
                                                   const float* __restrict__ b0,
                                                   const float* __restrict__ b1,
                                                   const float* __restrict__ b2,
                                                   bf16* __restrict__ qb,
                                                   bf16* __restrict__ kb,
                                                   bf16* __restrict__ Vt) {
    __shared__ alignas(16) bf16 LDS[3 * 12288];  // per buf: A 256x32 @0 | B 128x32 @8192

    // XCD-chunked bijective swizzle (768 % 8 == 0): contiguous work chunk per XCD.
    const int orig = blockIdx.x;
    const int swz = (orig & 7) * 96 + (orig >> 3);
    const int by = swz / 24, bx = swz % 24;
    const int m0 = by * 256, n0 = bx * 128;

    const int tid = threadIdx.x;
    const int wid = tid >> 6, lane = tid & 63;
    const int wr = wid;  // 4 waves, M-split only; per-wave out 64x128
    const int quad = lane >> 4, l16 = lane & 15;

    // staging: 256 threads x 6 gld_lds. 16B chunks: A = 1024 chunks (4/thread, instr
    // j=0..3 covers id=j*256+t), B = 512 chunks (2/thread, j=4..5, id=(j-4)*256+t).
    // id -> row=id>>2, kc=id&3; source chunk pre-swizzled kc^((row>>1)&3); LDS dest
    // id*8 elements (linear in t per instruction -> gld_lds lane rule satisfied).
    const bf16* gsrc[6];
    int ldst[6];
#pragma unroll
    for (int j = 0; j < 6; j++) {
        const int id = (j < 4) ? (j * 256 + tid) : ((j - 4) * 256 + tid);
        const int row = id >> 2, kc = id & 3;
        const int sc = (kc ^ ((row >> 1) & 3)) * 8;
        if (j < 4) {
            gsrc[j] = A + (size_t)(m0 + row) * 1024 + sc;
            ldst[j] = id * 8;
        } else {
            gsrc[j] = Bt + (size_t)(n0 + row) * 1024 + sc;
            ldst[j] = 8192 + id * 8;
        }
    }

    // read-side swizzled chunk: (row>>1)&3 == (l16>>1)&3 for all fragment rows
    const int coff = ((quad ^ ((l16 >> 1) & 3)) * 8);

    f32x4 acc[4][8] = {};

    auto STAGE = [&](int kt, int p) {
        const int base = p * 12288;
#pragma unroll
        for (int j = 0; j < 6; j++) gld_lds16(gsrc[j] + kt * 32, &LDS[base + ldst[j]]);
    };

    STAGE(0, 0);
    STAGE(1, 1);
    VWAIT6();  // drain STAGE(0); STAGE(1)'s 6 loads stay in flight
    PBAR();

    int rb = 0;   // read buffer for kt
    int sb = 2;   // stage buffer for kt+2
#pragma unroll 1
    for (int kt = 0; kt < 32; kt++) {
        const bf16* Asp = &LDS[rb * 12288];
        const bf16* Bsp = Asp + 8192;
        if (kt + 2 < 32) STAGE(kt + 2, sb);  // buf freed at kt-1's closing barrier

        bf16x8 af[4], bfr[8];
#pragma unroll
        for (int m4 = 0; m4 < 4; m4++)
            af[m4] = *(const bf16x8*)&Asp[(wr * 64 + m4 * 16 + l16) * 32 + coff];
#pragma unroll
        for (int ni = 0; ni < 8; ni++)
            bfr[ni] = *(const bf16x8*)&Bsp[(ni * 16 + l16) * 32 + coff];

        __builtin_amdgcn_s_setprio(1);
#pragma unroll
        for (int m4 = 0; m4 < 4; m4++)
#pragma unroll
            for (int ni = 0; ni < 8; ni++)
                acc[m4][ni] = MFMA16(af[m4], bfr[ni], acc[m4][ni]);
        __builtin_amdgcn_s_setprio(0);

        if (kt < 30) {
            VWAIT6();  // drain stage(kt+1); stage(kt+2)'s 6 loads fly across the barrier
            PBAR();
        } else if (kt == 30) {
            VWAIT0();  // last outstanding: STAGE(31)
            PBAR();
        }
        rb = (rb == 2) ? 0 : rb + 1;
        sb = (sb == 2) ? 0 : sb + 1;
    }

    // epilogue (per-wave 64 rows x full 128-col tile; 128 | 1024 -> never straddles)
    const int nl0 = n0 & 1023;
    const int sel = n0 >> 10;  // 0=q, 1=k, 2=v
    const int mb0 = m0 + wr * 64;
    if (sel < 2) {
        const float* bias = (sel == 0) ? b0 : b1;
        bf16* Cp = (sel == 0) ? qb : kb;
        const float qs = (sel == 0) ? SM_SCALE : 1.0f;
#pragma unroll
        for (int mi = 0; mi < 4; mi++) {
            const int mbase = mb0 + mi * 16 + quad * 4;
#pragma unroll
            for (int ni = 0; ni < 8; ni++) {
                const int nl = nl0 + ni * 16 + l16;
                const float bv = bias[nl];
#pragma unroll
                for (int r = 0; r < 4; r++)
                    Cp[(size_t)(mbase + r) * 1024 + nl] = (bf16)((acc[mi][ni][r] + bv) * qs);
            }
        }
    } else {
        const int b = m0 >> 11;  // 2048 rows/batch; 256-row block never straddles
#pragma unroll
        for (int ni = 0; ni < 8; ni++) {
            const int nl = nl0 + ni * 16 + l16;
            const int h = nl >> 6, d = nl & 63;
            const float bv = b2[nl];
            bf16* dst = Vt + ((size_t)(b * 16 + h) * 64 + d) * 2048;
#pragma unroll
            for (int mi = 0; mi < 4; mi++) {
                const int t0 = (mb0 + mi * 16 + quad * 4) & 2047;  // batch-local t
                bf16x4 w = {(bf16)(acc[mi][ni][0] + bv), (bf16)(acc[mi][ni][1] + bv),
                            (bf16)(acc[mi][ni][2] + bv), (bf16)(acc[mi][ni][3] + bv)};
                *(bf16x4*)&dst[t0] = w;
            }
        }
    }
}

// ---------------- proj GEMM: 256x128 tile, BK=32, 8 waves (4Mx2N), 3-buf (R14) ----------------
__global__ __launch_bounds__(512, 4) void gemm_proj(const bf16* __restrict__ A,
                                                    const bf16* __restrict__ Bt,
                                                    const float* __restrict__ b0,
                                                    float* __restrict__ out0,
                                                    int nbx) {
    __shared__ alignas(16) bf16 LDS[3 * 12288];  // per buf: A 256x32 @0 | B 128x32 @8192

    const int orig = blockIdx.x;
    const int chunk = (int)gridDim.x >> 3;
    const int swz = (orig & 7) * chunk + (orig >> 3);
    const int by = swz / nbx, bx = swz % nbx;
    const int m0 = by * 256, n0 = bx * 128;

    const int tid = threadIdx.x;
    const int wid = tid >> 6, lane = tid & 63;
    const int wr = wid >> 1, wc = wid & 1;  // wave grid 4M x 2N; per-wave out 64x64
    const int quad = lane >> 4, l16 = lane & 15;

    const int sr = tid >> 2;
    const int scol = (((tid & 3) ^ ((sr >> 1) & 3)) * 8);
    const bf16* gA = A + (size_t)(m0 + sr) * 1024 + scol;
    const bf16* gB = Bt + (size_t)(n0 + sr) * 1024 + scol;
    bf16* lA = &LDS[tid * 8];
    bf16* lB = &LDS[8192 + tid * 8];

    const int coff = ((quad ^ ((l16 >> 1) & 3)) * 8);

    f32x4 acc[4][4] = {};

    auto STAGE = [&](int kt, int p) {
        const int base = p * 12288;
        gld_lds16(gA + kt * 32, lA + base);
        gld_lds16(gA + kt * 32 + (size_t)128 * 1024, lA + base + 4096);
        gld_lds16(gB + kt * 32, lB + base);
    };

    STAGE(0, 0);
    STAGE(1, 1);
    VWAIT3();
    PBAR();

    int rb = 0, sb = 2;
#pragma unroll 1
    for (int kt = 0; kt < 32; kt++) {
        const bf16* Asp = &LDS[rb * 12288];
        const bf16* Bsp = Asp + 8192;
        if (kt + 2 < 32) STAGE(kt + 2, sb);

        bf16x8 af[4], bfr[4];
#pragma unroll
        for (int m4 = 0; m4 < 4; m4++)
            af[m4] = *(const bf16x8*)&Asp[(wr * 64 + m4 * 16 + l16) * 32 + coff];
#pragma unroll
        for (int ni = 0; ni < 4; ni++)
            bfr[ni] = *(const bf16x8*)&Bsp[(wc * 64 + ni * 16 + l16) * 32 + coff];

        __builtin_amdgcn_s_setprio(1);
#pragma unroll
        for (int m4 = 0; m4 < 4; m4++)
#pragma unroll
            for (int ni = 0; ni < 4; ni++)
                acc[m4][ni] = MFMA16(af[m4], bfr[ni], acc[m4][ni]);
        __builtin_amdgcn_s_setprio(0);

        if (kt < 30) {
            VWAIT3();
            PBAR();
        } else if (kt == 30) {
            VWAIT0();
            PBAR();
        }
        rb = (rb == 2) ? 0 : rb + 1;
        sb = (sb == 2) ? 0 : sb + 1;
    }

    const int mb0 = m0 + wr * 64;
#pragma unroll
    for (int mi = 0; mi < 4; mi++) {
        const int mbase = mb0 + mi * 16 + quad * 4;
#pragma unroll
        for (int ni = 0; ni < 4; ni++) {
            const int n = n0 + wc * 64 + ni * 16 + l16;
            const float bv = b0[n];
#pragma unroll
            for (int r = 0; r < 4; r++)
                out0[(size_t)(mbase + r) * 1024 + n] = acc[mi][ni][r] + bv;
        }
    }
}

// ---------------- flash attention, causal, hs=64 (R17 structure, unchanged) ----------------
template <bool NEEDMASK>
__device__ __forceinline__ void softmax_reg(const f32x4* st, bf16x8* pf, int qrel) {
    unsigned int p[4][2];
#pragma unroll
    for (int j = 0; j < 4; j++) {
        float pv[4];
#pragma unroll
        for (int r = 0; r < 4; r++) {
            float s = st[j][r];
            if (NEEDMASK && (j * 16 + r > qrel)) s = -1e30f;
            pv[r] = __builtin_amdgcn_exp2f(s);
        }
        bf16x2 w0 = {(bf16)pv[0], (bf16)pv[1]};  // v_cvt_pk_bf16_f32 (compiler-fused)
        bf16x2 w1 = {(bf16)pv[2], (bf16)pv[3]};
        p[j][0] = __builtin_bit_cast(unsigned int, w0);
        p[j][1] = __builtin_bit_cast(unsigned int, w1);
    }
    // acc layout -> B-frag layout: permlane32_swap then permlane16_swap (l16 invariant)
#pragma unroll
    for (int ks = 0; ks < 2; ks++) {
        unsigned int q4[4];
#pragma unroll
        for (int h = 0; h < 2; h++) {
            u32x2 s32 = __builtin_amdgcn_permlane32_swap(p[2 * ks][h], p[2 * ks + 1][h],
                                                         false, false);
            u32x2 s16 = __builtin_amdgcn_permlane16_swap(s32[0], s32[1], false, false);
            q4[h] = s16[0];      // e2 = h     (kv ofs 2h, 2h+1)
            q4[2 + h] = s16[1];  // e2 = 2+h   (kv ofs 4+2h, 5+2h)
        }
        u32x4 qq = {q4[0], q4[1], q4[2], q4[3]};
        pf[ks] = __builtin_bit_cast(bf16x8, qq);
    }
}

__global__ __launch_bounds__(256, 2) void attn(const bf16* __restrict__ Q,
                                               const bf16* __restrict__ Kg,
                                               const bf16* __restrict__ Vt,
                                               bf16* __restrict__ O) {
    // bijective XCD swizzle: 512 blocks; lin%8 = XCD -> 8 whole (b,h) heads per XCD.
    const int lin = blockIdx.x;
    const int bh = (lin & 7) * 8 + ((lin >> 3) & 7);
    const int jb = lin >> 6;  // [0,8)
    const int b = bh >> 4, h = bh & 15;
    const int tid = threadIdx.x;
    const int wave = tid >> 6, lane = tid & 63;
    const int quad = lane >> 4, l16 = lane & 15;

    __shared__ alignas(16) bf16 KVs[3 * 8192];  // 3-buf; per buf: K 64x64 | V^T 64x64 (swz)

    const bf16* Kbase = Kg + ((size_t)b * 2048) * 1024 + h * 64;
    const bf16* Vbase = Vt + (size_t)bh * 64 * 2048;

    const int srow = tid >> 3;
    const int schunk = (tid & 7) ^ (srow & 7);

    const int xorE = (l16 & 7) * 8;
    const int cofA = (quad * 8) ^ xorE;       // ks=0
    const int cofB = (32 + quad * 8) ^ xorE;  // ks=1

    const bf16 one1 = (bf16)1.0f;
    const bf16x8 onesf = {one1, one1, one1, one1, one1, one1, one1, one1};

#pragma unroll 1
    for (int phase = 0; phase < 2; phase++) {
        // strip pairing at 128-q granularity: (15-jb) then jb -> 36 tiles total
        const int js = (phase == 0) ? (15 - jb) : jb;
        const int q0 = js * 128;
        const bf16* Qbase = Q + ((size_t)(b * 2048 + q0)) * 1024 + h * 64;

        // Q fragments for both strips (A: rows 0-63, B: rows 64-127 of the q-block)
        bf16x8 qfA[2], qfB[2];
#pragma unroll
        for (int ks = 0; ks < 2; ks++) {
            qfA[ks] = *(const bf16x8*)&Qbase[(size_t)(wave * 16 + l16) * 1024 + ks * 32 + quad * 8];
            qfB[ks] = *(const bf16x8*)&Qbase[(size_t)(64 + wave * 16 + l16) * 1024 + ks * 32 + quad * 8];
        }

        f32x4 otA[4] = {}, otB[4] = {};
        f32x4 laccA = {0.f, 0.f, 0.f, 0.f}, laccB = {0.f, 0.f, 0.f, 0.f};
        const int ntiles = 2 * js + 2;
        const int qrel = wave * 16 + l16 - quad * 4;

        const bf16* pK = Kbase + (size_t)srow * 1024 + schunk * 8;
        const bf16* pK2 = pK + (size_t)32 * 1024;
        const bf16* pV = Vbase + (size_t)srow * 2048 + schunk * 8;
        const bf16* pV2 = pV + (size_t)32 * 2048;

        // prologue: stage tiles 0 and 1 (ntiles >= 2 always)
        {
            bf16* nb = &KVs[tid * 8];
            gld_lds16(pK, nb);
            gld_lds16(pK2, nb + 2048);
            gld_lds16(pV, nb + 4096);
            gld_lds16(pV2, nb + 6144);
            pK += 64 * 1024; pK2 += 64 * 1024; pV += 64; pV2 += 64;
            nb = &KVs[8192 + tid * 8];
            gld_lds16(pK, nb);
            gld_lds16(pK2, nb + 2048);
            gld_lds16(pV, nb + 4096);
            gld_lds16(pV2, nb + 6144);
            pK += 64 * 1024; pK2 += 64 * 1024; pV += 64; pV2 += 64;
        }
        VWAIT4();  // drain stage(0); stage(1) stays in flight
        PBAR();

        int rbuf = 0, sbuf = 2;
#pragma unroll 1
        for (int tk = 0; tk < ntiles - 1; tk++) {
            const bf16* buf = &KVs[rbuf * 8192];
            if (tk + 2 < ntiles) {  // stage(t+2): drained at t+1's end (2 bodies away)
                bf16* nb = &KVs[sbuf * 8192 + tid * 8];
                gld_lds16(pK, nb);
                gld_lds16(pK2, nb + 2048);
                gld_lds16(pV, nb + 4096);
                gld_lds16(pV2, nb + 6144);
                pK += 64 * 1024; pK2 += 64 * 1024; pV += 64; pV2 += 64;
            }

            // S^T = K . Q^T for both strips; each kf read feeds 2 MFMAs
            f32x4 stA[4] = {}, stB[4] = {};
            __builtin_amdgcn_s_setprio(1);
#pragma unroll
            for (int ks = 0; ks < 2; ks++)
#pragma unroll
                for (int j = 0; j < 4; j++) {
                    const bf16x8 kf =
                        *(const bf16x8*)&buf[(j * 16 + l16) * 64 + (ks ? cofB : cofA)];
                    stA[j] = MFMA16(kf, qfA[ks], stA[j]);
                    stB[j] = MFMA16(kf, qfB[ks], stB[j]);
                }
            __builtin_amdgcn_s_setprio(0);

            // softmax per strip (A's diagonal at ntiles-2; B unmasked in-loop)
            bf16x8 pfA[2], pfB[2];
            if (tk == ntiles - 2) {
                softmax_reg<true>(stA, pfA, qrel);
                softmax_reg<false>(stB, pfB, qrel);
            } else {
                softmax_reg<false>(stA, pfA, qrel);
                softmax_reg<false>(stB, pfB, qrel);
            }

            // l-sums via MFMA ones-fragment
            laccA = MFMA16(onesf, pfA[0], laccA);
            laccA = MFMA16(onesf, pfA[1], laccA);
            laccB = MFMA16(onesf, pfB[0], laccB);
            laccB = MFMA16(onesf, pfB[1], laccB);

            // O^T += V^T . P^T; each vf read feeds 2 MFMAs
            __builtin_amdgcn_s_setprio(1);
#pragma unroll
            for (int ks = 0; ks < 2; ks++)
#pragma unroll
                for (int db = 0; db < 4; db++) {
                    const bf16x8 vf = *(const bf16x8*)&buf[4096 + (db * 16 + l16) * 64 +
                                                           (ks ? cofB : cofA)];
                    otA[db] = MFMA16(vf, pfA[ks], otA[db]);
                    otB[db] = MFMA16(vf, pfB[ks], otB[db]);
                }
            __builtin_amdgcn_s_setprio(0);

            if (tk + 2 < ntiles) VWAIT4();  // drain stage(t+1); stage(t+2) in flight
            else VWAIT0();                  // tail: drain the last stage
            PBAR();                         // publish t+1; buf[rbuf] readers done
            rbuf = (rbuf == 2) ? 0 : rbuf + 1;
            sbuf = (sbuf == 2) ? 0 : sbuf + 1;
        }

        // peeled final tile: strip B's diagonal. Strip A fully masked here (qrel-64 < 0
        // -> pfA == 0): its QK/softmax/l/PV all contribute zeros -> skipped entirely.
        {
            const bf16* buf = &KVs[rbuf * 8192];
            f32x4 stB[4] = {};
            __builtin_amdgcn_s_setprio(1);
#pragma unroll
            for (int ks = 0; ks < 2; ks++)
#pragma unroll
                for (int j = 0; j < 4; j++) {
                    const bf16x8 kf =
                        *(const bf16x8*)&buf[(j * 16 + l16) * 64 + (ks ? cofB : cofA)];
                    stB[j] = MFMA16(kf, qfB[ks], stB[j]);
                }
            __builtin_amdgcn_s_setprio(0);
            bf16x8 pfB[2];
            softmax_reg<true>(stB, pfB, qrel);
            laccB = MFMA16(onesf, pfB[0], laccB);
            laccB = MFMA16(onesf, pfB[1], laccB);
            __builtin_amdgcn_s_setprio(1);
#pragma unroll
            for (int ks = 0; ks < 2; ks++)
#pragma unroll
                for (int db = 0; db < 4; db++) {
                    const bf16x8 vf = *(const bf16x8*)&buf[4096 + (db * 16 + l16) * 64 +
                                                           (ks ? cofB : cofA)];
                    otB[db] = MFMA16(vf, pfB[ks], otB[db]);
                }
            __builtin_amdgcn_s_setprio(0);
        }

        // epilogue: per strip, O^T regs -> transpose scratch in buf[(ntiles+1)%3]
        // (!= peeled tile's buffer; its prior readers finished at the last in-loop
        // barrier). Strips sequential through the same per-wave 16x72 region
        // (same-wave LDS ops are in-order -> WAR safe).
        bf16* ep = &KVs[((ntiles + 1) % 3) * 8192 + wave * (16 * 72)];
        const int orow = lane >> 2, oc = (lane & 3) * 16;
        {
            const float inv = 1.f / laccA[0];
#pragma unroll
            for (int db = 0; db < 4; db++) {
                bf16x4 w = {(bf16)(otA[db][0] * inv), (bf16)(otA[db][1] * inv),
                            (bf16)(otA[db][2] * inv), (bf16)(otA[db][3] * inv)};
                *(bf16x4*)&ep[l16 * 72 + db * 16 + quad * 4] = w;
            }
            bf16* Obase =
                O + ((size_t)(b * 2048 + q0 + wave * 16 + orow)) * 1024 + h * 64 + oc;
            const bf16* src = &ep[orow * 72 + oc];
            *(bf16x8*)&Obase[0] = *(const bf16x8*)&src[0];
            *(bf16x8*)&Obase[8] = *(const bf16x8*)&src[8];
        }
        {
            const float inv = 1.f / laccB[0];
#pragma unroll
            for (int db = 0; db < 4; db++) {
                bf16x4 w = {(bf16)(otB[db][0] * inv), (bf16)(otB[db][1] * inv),
                            (bf16)(otB[db][2] * inv), (bf16)(otB[db][3] * inv)};
                *(bf16x4*)&ep[l16 * 72 + db * 16 + quad * 4] = w;
            }
            bf16* Obase =
                O + ((size_t)(b * 2048 + q0 + 64 + wave * 16 + orow)) * 1024 + h * 64 + oc;
            const bf16* src = &ep[orow * 72 + oc];
            *(bf16x8*)&Obase[0] = *(const bf16x8*)&src[0];
            *(bf16x8*)&Obase[8] = *(const bf16x8*)&src[8];
        }
        __syncthreads();  // all buffers drained + epilogue reads done before next phase
    }
}

extern "C" void kernel_launch(void* const* d_in, const int* in_sizes, int n_in,
                              void* d_out, int out_size, void* d_ws, size_t ws_size,
                              hipStream_t stream) {
    const float* x = (const float*)d_in[0];
    const float* Wq = (const float*)d_in[1];
    const float* bq = (const float*)d_in[2];
    const float* Wk = (const float*)d_in[3];
    const float* bk = (const float*)d_in[4];
    const float* Wv = (const float*)d_in[5];
    const float* bv = (const float*)d_in[6];
    float* out = (float*)d_out;

    const int M = 8192;  // B*T
    const size_t sz_x = (size_t)M * 1024;
    const size_t sz_w = (size_t)1024 * 1024;

    char* p = (char*)d_ws;
    bf16* xb = (bf16*)p;   p += sz_x * 2;
    bf16* Wcat = (bf16*)p; p += 3 * sz_w * 2;  // [Wq^T ; Wk^T ; Wv^T]
    bf16* qb = (bf16*)p;   p += sz_x * 2;
    bf16* kb = (bf16*)p;   p += sz_x * 2;
    bf16* Vt = (bf16*)p;   p += sz_x * 2;  // [B*H][64][2048]
    bf16* yatt = (bf16*)p; p += sz_x * 2;

    // W transpose + x convert in one launch
    prep<<<dim3(2816), dim3(256), 0, stream>>>(Wq, Wk, Wv, Wcat, x, xb);

    // fused QKV projection: [8192,1024] @ [1024,3072] -- 256x128, 4 waves of 64x128
    gemm_qkv<<<dim3(768), dim3(256), 0, stream>>>(xb, Wcat, bq, bk, bv, qb, kb, Vt);
    attn<<<dim3(512), dim3(256), 0, stream>>>(qb, kb, Vt, yatt);
    // output projection (reference reuses v_proj): BM=256, grid 256
    gemm_proj<<<dim3(256), dim3(512), 0, stream>>>(yatt, Wcat + 2 * sz_w, bv, out, 8);
}